// Round 7
// baseline (2480.410 us; speedup 1.0000x reference)
//
// R7: TM=64, 2 independent blocks/CU for true MFMA/VALU overlap.
// R6 post-mortem: MfmaUtil 40.7 + VALUBusy 37.5 = 78% serialized — both
// waves/SIMD barrier-locked in the same phase; need independent streams.
// Split: 2048 blocks x 512 thr; 8 waves = 4r x 2c, wave = 32 h-rows x 32 cols.
// Weights/wave: 9+9 frags = 72 regs (+acc 16) -> target <=128 total regs via
// __launch_bounds__(512,4) = 4 waves/SIMD = 2 blocks/CU.
// Single hx exchange buffer (L2 then L3), 5 barriers/step; Wf via broadcast
// global loads (L2-resident); part_s separate (no alias race).
// LDS: o 16K + wx 32K + hx 16K + part 1K = 65KB -> 2 blocks/CU w/ margin.
// Predicted: Occ ~46%, MfmaUtil 55-70, 1250-1500us, conflicts ~1.5e6,
// WRITE 110-160MB (>>250MB = spill-storm failure signature).

#include <hip/hip_runtime.h>
#include <hip/hip_bf16.h>

typedef __bf16 bf16x8 __attribute__((ext_vector_type(8)));
typedef float  f32x16 __attribute__((ext_vector_type(16)));

#define AS1 __attribute__((address_space(1)))
#define AS3 __attribute__((address_space(3)))

#define NROWS 131072u
#define TM    64u

// ---------- helpers ----------
static __device__ __forceinline__ unsigned short bf16r(float x){ // RNE f32->bf16
  unsigned u = __builtin_bit_cast(unsigned, x);
  u = (u + 0x7FFFu + ((u >> 16) & 1u)) >> 16;
  return (unsigned short)u;
}
static __device__ __forceinline__ unsigned pk2c(float lo, float hi){
  unsigned d;
  asm("v_cvt_pk_bf16_f32 %0, %1, %2" : "=v"(d) : "v"(lo), "v"(hi));
  return d; // lo16 = bf16(lo), hi16 = bf16(hi)
}
static __device__ __forceinline__ bf16x8 mkfrag(unsigned a, unsigned b, unsigned c, unsigned d){
  uint4 t; t.x = a; t.y = b; t.z = c; t.w = d;
  return __builtin_bit_cast(bf16x8, t);
}
static __device__ __forceinline__ bf16x8 u4frag(const uint4 v){
  return __builtin_bit_cast(bf16x8, v);
}
static __device__ __forceinline__ bf16x8 ldfrag(const unsigned short* base, unsigned byteoff){
  const uint4 v = *(const uint4*)((const char*)base + byteoff);
  return __builtin_bit_cast(bf16x8, v);
}
static __device__ __forceinline__ f32x16 zero16(){
  f32x16 v;
  #pragma unroll
  for (int j = 0; j < 16; ++j) v[j] = 0.0f;
  return v;
}
static __device__ __forceinline__ void relu16(f32x16& a){
  #pragma unroll
  for (int j = 0; j < 16; ++j) a[j] = fmaxf(a[j], 0.0f);
}
// Pack a relu'd 32x32 acc tile into next-layer B-frags (R2/R6-HW-validated).
static __device__ __forceinline__ void buildfr(const f32x16& a, uint4& lo, uint4& hi){
  unsigned p0 = pk2c(a[0],a[1]),  p1 = pk2c(a[2],a[3]);
  unsigned p2 = pk2c(a[4],a[5]),  p3 = pk2c(a[6],a[7]);
  unsigned q0 = pk2c(a[8],a[9]),  q1 = pk2c(a[10],a[11]);
  unsigned q2 = pk2c(a[12],a[13]),q3 = pk2c(a[14],a[15]);
  { auto r = __builtin_amdgcn_permlane32_swap(p0, p2, false, false); lo.x=r[0]; lo.z=r[1]; }
  { auto r = __builtin_amdgcn_permlane32_swap(p1, p3, false, false); lo.y=r[0]; lo.w=r[1]; }
  { auto r = __builtin_amdgcn_permlane32_swap(q0, q2, false, false); hi.x=r[0]; hi.z=r[1]; }
  { auto r = __builtin_amdgcn_permlane32_swap(q1, q3, false, false); hi.y=r[0]; hi.w=r[1]; }
}
// Stage the 32KB pre-swizzled Wx image for step i into LDS (linear, 8 waves).
static __device__ __forceinline__ void stage(const unsigned short* __restrict__ wxp,
                                             unsigned short* wx_lds,
                                             unsigned i, unsigned wid, unsigned lane){
  const char* src = (const char*)wxp + (size_t)i*32768u + wid*4096u + lane*16u;
  char* dst = (char*)wx_lds + wid*4096u;            // wave-uniform base; HW adds lane*16
  #pragma unroll
  for (unsigned c = 0; c < 4; ++c)
    __builtin_amdgcn_global_load_lds((const AS1 unsigned*)(src + c*1024u),
                                     (AS3 unsigned*)(dst + c*1024u), 16, 0, 0);
}

// ---------- prep kernels (unchanged, validated) ----------
__global__ __launch_bounds__(256) void prep_w(const float* __restrict__ Wi,
                                              const float* __restrict__ M,
                                              const float* __restrict__ bi,
                                              unsigned short* __restrict__ wxp,
                                              unsigned* __restrict__ extimg){
  const unsigned i = blockIdx.x, tid = threadIdx.x;
  __shared__ float mcol[128];
  if (tid < 128u) mcol[tid] = (tid == i) ? 0.0f : M[tid*128u + i];
  __syncthreads();
  const float* wrow = Wi + (size_t)i*128u*129u;
  unsigned short* dst = wxp + (size_t)i*16384u;
  #pragma unroll 4
  for (unsigned p = 0; p < 64; ++p){
    unsigned e = p*256u + tid;
    unsigned hh = e >> 7, j = e & 127u;
    float v = wrow[hh*129u + j] * mcol[j];
    dst[hh*128u + ((((j>>3) ^ (hh & 15u)) << 3) | (j & 7u))] = bf16r(v);
  }
  if (tid < 128u){
    float wz = wrow[tid*129u + 128u];
    float bv = bi[i*128u + tid];
    extimg[i*128u + tid] = (unsigned)bf16r(wz) | ((unsigned)bf16r(bv) << 16);
  }
}
__global__ __launch_bounds__(256) void prep_z(const float* __restrict__ z,
                                              unsigned short* __restrict__ zT){
  __shared__ float t[64][129];
  const unsigned tid = threadIdx.x, b0 = blockIdx.x * 64u;
  #pragma unroll 4
  for (unsigned p = 0; p < 32; ++p){
    unsigned e = p*256u + tid;
    t[e >> 7][e & 127u] = z[(size_t)b0*128u + e];
  }
  __syncthreads();
  #pragma unroll 4
  for (unsigned p = 0; p < 32; ++p){
    unsigned e = p*256u + tid;
    unsigned ii = e >> 6, bb = e & 63u;
    zT[(size_t)ii*NROWS + b0 + bb] = bf16r(t[bb][ii]);
  }
}

// ---------- main persistent scan kernel ----------
__global__ __launch_bounds__(512, 4) void gen_main(
    const float* __restrict__ x,   const float* __restrict__ Wf,
    const float* __restrict__ bfp, const float* __restrict__ W1,
    const float* __restrict__ b1,  const float* __restrict__ W2,
    const float* __restrict__ b2,  const unsigned short* __restrict__ wxp,
    const unsigned* __restrict__ extimg, const unsigned short* __restrict__ zT,
    float* __restrict__ out)
{
  __shared__ unsigned short o_lds[8192];    // 64 x 128 bf16, swizzled (16KB)
  __shared__ unsigned short wx_lds[16384];  // per-step Wx image (32KB)
  __shared__ unsigned short hx_lds[8192];   // 64 rows x 16 slots x 16B (16KB)
  __shared__ float part_s[256];             // [r][bcol] epilogue partials (1KB)

  const unsigned tid  = threadIdx.x;
  const unsigned wid  = tid >> 6, lane = tid & 63u;
  const unsigned l31  = lane & 31u, hf = lane >> 5;
  const unsigned rr_  = wid >> 1, cc_ = wid & 1u;   // 4 h-row groups x 2 col groups
  const unsigned r0   = blockIdx.x * TM;
  const unsigned bcol = cc_*32u + l31;              // owned batch col (0..63)

  // o_lds <- bf16(x) (swizzled)
  #pragma unroll 4
  for (unsigned p = 0; p < 16; ++p){
    unsigned e = p*512u + tid;
    unsigned row = e >> 7, col = e & 127u;
    float v = x[(size_t)r0*128u + e];
    o_lds[row*128u + ((((col>>3) ^ (row & 15u)) << 3) | (col & 7u))] = bf16r(v);
  }

  // Window order: [own 2r, own 2r+1, partners ascending]; slot j compile-time.
  unsigned widx[8];
  widx[0] = 2u*rr_; widx[1] = 2u*rr_ + 1u;
  #pragma unroll
  for (unsigned j = 0; j < 6; ++j) widx[2u+j] = (j < 2u*rr_) ? j : j + 2u;

  // Per-wave weight slices: rows 32rr_+l31, window widx[j] (+ K-ext bias frag)
  const unsigned hrow = 32u*rr_ + l31;
  bf16x8 w1f[9], w2f[9];
  #pragma unroll
  for (unsigned j = 0; j < 8; ++j){
    const unsigned w = widx[j];
    const float4 a0 = *(const float4*)(W1 + hrow*128u + w*16u + hf*8u);
    const float4 a1 = *(const float4*)(W1 + hrow*128u + w*16u + hf*8u + 4u);
    w1f[j] = mkfrag(pk2c(a0.x,a0.y), pk2c(a0.z,a0.w), pk2c(a1.x,a1.y), pk2c(a1.z,a1.w));
    const float4 c0 = *(const float4*)(W2 + hrow*128u + w*16u + hf*8u);
    const float4 c1 = *(const float4*)(W2 + hrow*128u + w*16u + hf*8u + 4u);
    w2f[j] = mkfrag(pk2c(c0.x,c0.y), pk2c(c0.z,c0.w), pk2c(c1.x,c1.y), pk2c(c1.z,c1.w));
  }
  w1f[8] = mkfrag(hf==0u ? (unsigned)bf16r(b1[hrow]) : 0u, 0u, 0u, 0u);
  w2f[8] = mkfrag(hf==0u ? (unsigned)bf16r(b2[hrow]) : 0u, 0u, 0u, 0u);
  const bf16x8 frext = mkfrag(hf==0u ? 0x00003F80u : 0u, 0u, 0u, 0u); // 1.0 @k-ext

  // Offsets (XOR slot pattern, conflict-free for b128 per R4/R6 measurements)
  unsigned offw[8];
  #pragma unroll
  for (unsigned w = 0; w < 8; ++w) offw[w] = ((2u*w + hf) ^ (l31 & 15u)) << 4;
  const unsigned rowA = hrow * 256u;
  const unsigned rowB = bcol * 256u;
  unsigned ow_off[2], po_off[6];
  #pragma unroll
  for (unsigned t = 0; t < 2; ++t)
    ow_off[t] = ((4u*rr_ + 2u*t + hf) ^ (l31 & 15u)) << 4;
  #pragma unroll
  for (unsigned j = 0; j < 6; ++j)
    po_off[j] = ((2u*widx[2u+j] + hf) ^ (l31 & 15u)) << 4;

  stage(wxp, wx_lds, 0u, wid, lane);
  __syncthreads();

  #pragma unroll 1
  for (unsigned i = 0; i < 128u; ++i){
    const unsigned short zb = zT[(size_t)i*NROWS + r0 + bcol];
    const unsigned eB = (hf == 0u) ? ((unsigned)zb | 0x3F800000u) : 0u;   // {z, 1.0}
    const unsigned ea = (hf == 0u) ? extimg[i*128u + hrow] : 0u;          // {wz, bi}
    const float bfi = bfp[i];

    // ---- L1: D1'[h][b] = Wx' * out^T (+ z*wz + bi via K-ext) ----
    f32x16 acc = __builtin_amdgcn_mfma_f32_32x32x16_bf16(
                   mkfrag(ea,0u,0u,0u), mkfrag(eB,0u,0u,0u), zero16(), 0, 0, 0);
    #pragma unroll
    for (unsigned w = 0; w < 8; ++w)
      acc = __builtin_amdgcn_mfma_f32_32x32x16_bf16(
              ldfrag(wx_lds, rowA + offw[w]), ldfrag(o_lds, rowB + offw[w]), acc, 0, 0, 0);
    relu16(acc);
    uint4 fl, fh;
    buildfr(acc, fl, fh);
    *(uint4*)((char*)hx_lds + rowB + ow_off[0]) = fl;   // own L1 frags -> hx
    *(uint4*)((char*)hx_lds + rowB + ow_off[1]) = fh;
    __syncthreads();                                    // B1: hx(L1) visible
    if (i + 1u < 128u) stage(wxp, wx_lds, i + 1u, wid, lane);

    // ---- L2: D2' = W1 * h1^T (+ b1 via K-ext) ----
    acc = __builtin_amdgcn_mfma_f32_32x32x16_bf16(w1f[8], frext, zero16(), 0, 0, 0);
    acc = __builtin_amdgcn_mfma_f32_32x32x16_bf16(w1f[0], u4frag(fl), acc, 0, 0, 0);
    acc = __builtin_amdgcn_mfma_f32_32x32x16_bf16(w1f[1], u4frag(fh), acc, 0, 0, 0);
    #pragma unroll
    for (unsigned j = 0; j < 6; ++j)
      acc = __builtin_amdgcn_mfma_f32_32x32x16_bf16(
              w1f[2u+j], ldfrag(hx_lds, rowB + po_off[j]), acc, 0, 0, 0);
    relu16(acc);
    buildfr(acc, fl, fh);
    __syncthreads();                                    // B2: hx(L1) read-drain
    *(uint4*)((char*)hx_lds + rowB + ow_off[0]) = fl;   // own L2 frags -> hx
    *(uint4*)((char*)hx_lds + rowB + ow_off[1]) = fh;
    __syncthreads();                                    // B3: hx(L2) visible

    // ---- L3: D3' = W2 * h2^T (+ b2 via K-ext) ----
    acc = __builtin_amdgcn_mfma_f32_32x32x16_bf16(w2f[8], frext, zero16(), 0, 0, 0);
    acc = __builtin_amdgcn_mfma_f32_32x32x16_bf16(w2f[0], u4frag(fl), acc, 0, 0, 0);
    acc = __builtin_amdgcn_mfma_f32_32x32x16_bf16(w2f[1], u4frag(fh), acc, 0, 0, 0);
    #pragma unroll
    for (unsigned j = 0; j < 6; ++j)
      acc = __builtin_amdgcn_mfma_f32_32x32x16_bf16(
              w2f[2u+j], ldfrag(hx_lds, rowB + po_off[j]), acc, 0, 0, 0);

    // ---- epilogue: partial dot with Wf over this wave's 32 h-rows ----
    // wfv[4j+e] = Wf[i][32rr_+4hf+8j+e]  (broadcast loads, L2/L3-resident)
    float s = 0.0f;
    #pragma unroll
    for (unsigned j = 0; j < 4; ++j){
      const float4 wv = *(const float4*)(Wf + i*128u + 32u*rr_ + 4u*hf + 8u*j);
      s += fmaxf(acc[4u*j+0u], 0.0f) * wv.x;
      s += fmaxf(acc[4u*j+1u], 0.0f) * wv.y;
      s += fmaxf(acc[4u*j+2u], 0.0f) * wv.z;
      s += fmaxf(acc[4u*j+3u], 0.0f) * wv.w;
    }
    s += __shfl_xor(s, 32, 64);                         // combine hf halves
    if (hf == 0u) part_s[rr_*64u + bcol] = s;
    __syncthreads();                                    // Bp: partials ready
    if (rr_ == 0u && hf == 0u){
      const float o = part_s[bcol] + part_s[64u + bcol] +
                      part_s[128u + bcol] + part_s[192u + bcol] + bfi;
      o_lds[bcol*128u + ((((i>>3) ^ (l31 & 15u)) << 3) | (i & 7u))] = bf16r(o);
      out[(size_t)(r0 + bcol)*128u + i] = o;
    }
    __syncthreads();                                    // B_end: o col visible
  }
}

// ---------- host ----------
extern "C" void kernel_launch(void* const* d_in, const int* in_sizes, int n_in,
                              void* d_out, int out_size, void* d_ws, size_t ws_size,
                              hipStream_t stream) {
  (void)in_sizes; (void)n_in; (void)out_size;
  const float* x  = (const float*)d_in[0];
  const float* z  = (const float*)d_in[1];
  const float* M  = (const float*)d_in[2];
  const float* Wi = (const float*)d_in[3];
  const float* bi = (const float*)d_in[4];
  const float* Wf = (const float*)d_in[5];
  const float* bf = (const float*)d_in[6];
  const float* W1 = (const float*)d_in[7];
  const float* b1 = (const float*)d_in[8];
  const float* W2 = (const float*)d_in[9];
  const float* b2 = (const float*)d_in[10];
  float* out = (float*)d_out;

  // ws layout: wxp 4MB | ext_img 64KB | zT 32MB  (total ~36.1MB)
  char* ws = (char*)d_ws;
  unsigned short* wxp    = (unsigned short*)ws;
  unsigned*       extimg = (unsigned*)(ws + 4194304u);
  unsigned short* zTp    = (unsigned short*)(ws + 4194304u + 65536u);
  (void)ws_size; // requires ws_size >= 37,814,272 bytes

  prep_w<<<128, 256, 0, stream>>>(Wi, M, bi, wxp, extimg);
  prep_z<<<NROWS/64u, 256, 0, stream>>>(z, zTp);
  gen_main<<<NROWS/TM, 512, 0, stream>>>(x, Wf, bf, W1, b1, W2, b2,
                                         wxp, extimg, zTp, out);
}